// Round 4
// baseline (172.671 us; speedup 1.0000x reference)
//
#include <hip/hip_runtime.h>

// SRL embeddings, fused single kernel — R6: R2 structure + persistent
// work-stealing blocks. Shapes fixed: B=16,S=16,L=128,D=768,A=8,T=5.
//
// R3/R5 post-mortem: CHUNK=16 (256B slices) costs ~+12us regardless of Phase B
// placement -> 512B slices are the floor geometry; CHUNK=32/BLOCK=256 locked.
// R6 mechanism: with grid==1536 all blocks are resident at t=0 (capacity 8/CU,
// offered 6/CU) -> no queue -> kernel ends at max over CUs of sum of 6 random
// prefix lens (~+23% tail on the stream phase). Fix: 1024 persistent blocks
// (4/CU, 16 waves/CU), item = (c,bs) of 1536; first item static
// (= blockIdx.x), rest claimed via global atomic counter in d_ws (zeroed by a
// 4-byte hipMemsetAsync; ~512 dynamic claims, no hotspot). Per-item body is
// R2 verbatim.

namespace {
constexpr int Bc = 16, Sc = 16, Lc = 128, Dc = 768, Ac = 8, Tc = 5;
constexpr int NF4    = Dc / 4;          // 192 float4 per row
constexpr int CHUNK  = 32;              // float4 columns per item (512B slice)
constexpr int NCHUNK = NF4 / CHUNK;     // 6
constexpr int BLOCK  = 256;             // 4 waves
constexpr int RP     = BLOCK / CHUNK;   // 8 l-phases
constexpr int NSLOT  = 3 * Ac;          // 24 arg slots
constexpr int OUT1   = Bc * Sc * NF4;       // sentence output, float4 units
constexpr int OUTG   = Bc * Sc * Ac * NF4;  // per-arg-type output, float4 units
constexpr int NBS    = Bc * Sc;         // 256 sentences
constexpr int NITEMS = NCHUNK * NBS;    // 1536 work items
constexpr int NGRID  = 1024;            // persistent blocks (4/CU)
}

__global__ __launch_bounds__(BLOCK) void srl_fused(
    const float4* __restrict__ hid,
    const int*    __restrict__ sids,
    const int*    __restrict__ amask,
    const int*    __restrict__ pids,
    const int*    __restrict__ a0ids,
    const int*    __restrict__ a1ids,
    float4*       __restrict__ out,
    int*          __restrict__ ctr)
{
  const int tid = threadIdx.x;
  const int q   = tid & (CHUNK - 1);    // float4 column within chunk
  const int r   = tid >> 5;             // l-phase 0..7

  __shared__ int    sid[Lc];
  __shared__ short  slist[NSLOT][Lc];
  __shared__ int    scnt[NSLOT];
  __shared__ float4 red[BLOCK];
  __shared__ int    item_s;

  int item = blockIdx.x;                // static first item (grid < NITEMS)

  for (;;) {
    if (item >= NITEMS) break;          // uniform across block
    const int c  = item >> 8;           // column chunk 0..5
    const int bs = item & (NBS - 1);    // (b,s) 0..255

    // Phase A: stage sentence ids; prefix length via __syncthreads_count.
    int mval = 0;
    if (tid < Lc) {
      sid[tid] = sids[bs * Lc + tid];
      mval     = amask[bs * Lc + tid];
    }
    const int len = __syncthreads_count(mval != 0);

    const float4* __restrict__ hrow = hid + (size_t)bs * Lc * NF4 + c * CHUNK;

    // Phase B (lanes 0..23 of wave 0, overlapped with pooling on waves 1..3):
    // count matches for all 5 tokens in one sid scan, pick LAST valid t
    // (tok!=0 && cnt>0), build its match list.
    if (tid < NSLOT) {
      const int g = tid / Ac, a = tid % Ac;
      const int* ids = (g == 0 ? pids : (g == 1 ? a0ids : a1ids)) + (bs * Ac + a) * Tc;
      int tok[Tc], cnt[Tc];
#pragma unroll
      for (int t = 0; t < Tc; ++t) { tok[t] = ids[t]; cnt[t] = 0; }
      for (int l = 0; l < Lc; ++l) {
        const int v = sid[l];   // broadcast read
#pragma unroll
        for (int t = 0; t < Tc; ++t) cnt[t] += (v == tok[t]) ? 1 : 0;
      }
      int sel = 0, n = 0;
#pragma unroll
      for (int t = Tc - 1; t >= 0; --t) {
        if (n == 0 && tok[t] != 0 && cnt[t] > 0) { sel = tok[t]; n = cnt[t]; }
      }
      scnt[tid] = n;
      if (n > 0) {
        int k = 0;
        for (int l = 0; l < Lc; ++l)
          if (sid[l] == sel) slist[tid][k++] = (short)l;
      }
    }

    // Phase C: pooling partial sums over the valid prefix, l-split by r.
    float ax = 0.f, ay = 0.f, az = 0.f, aw = 0.f;
#pragma unroll 4
    for (int l = r; l < len; l += RP) {
      const float4 v = hrow[l * NF4 + q];
      ax += v.x; ay += v.y; az += v.z; aw += v.w;
    }
    red[tid] = make_float4(ax, ay, az, aw);
    __syncthreads();   // red ready; also publishes scnt/slist for Phase D

    // Phase C2: reduce the 8 l-phases, divide by len, write sentence embedding.
    if (tid < CHUNK) {
      float4 s = red[q];
#pragma unroll
      for (int p = 1; p < RP; ++p) {
        const float4 t = red[p * CHUNK + q];
        s.x += t.x; s.y += t.y; s.z += t.z; s.w += t.w;
      }
      const float inv = 1.0f / (float)(len > 0 ? len : 1);
      s.x *= inv; s.y *= inv; s.z *= inv; s.w *= inv;
      out[bs * NF4 + c * CHUNK + q] = s;
    }

    // Phase D: arg embeddings. 3 slots per l-phase; match rows hit L1/L2
    // (same columns streamed in Phase C).
    for (int j = r; j < NSLOT; j += RP) {
      const int n = scnt[j];
      float ox = 0.f, oy = 0.f, oz = 0.f, ow = 0.f;
      if (n > 0) {
        for (int i = 0; i < n; ++i) {
          const int l = (int)slist[j][i];   // broadcast read
          const float4 v = hrow[l * NF4 + q];
          ox += v.x; oy += v.y; oz += v.z; ow += v.w;
        }
        const float inv = 1.0f / (float)n;
        ox *= inv; oy *= inv; oz *= inv; ow *= inv;
      }
      const int g = j / Ac, a = j - g * Ac;
      out[OUT1 + g * OUTG + (bs * Ac + a) * NF4 + c * CHUNK + q] =
          make_float4(ox, oy, oz, ow);
    }

    // Claim next item (Phase D still reading slist -> barrier first).
    __syncthreads();
    if (tid == 0) item_s = NGRID + atomicAdd(ctr, 1);
    __syncthreads();
    item = item_s;
  }
}

extern "C" void kernel_launch(void* const* d_in, const int* in_sizes, int n_in,
                              void* d_out, int out_size, void* d_ws, size_t ws_size,
                              hipStream_t stream) {
  const float4* hid   = (const float4*)d_in[0];
  const int*    sids  = (const int*)d_in[1];
  const int*    amask = (const int*)d_in[2];
  const int*    pids  = (const int*)d_in[3];
  const int*    a0ids = (const int*)d_in[4];
  const int*    a1ids = (const int*)d_in[5];
  float4*       out   = (float4*)d_out;
  int*          ctr   = (int*)d_ws;

  hipMemsetAsync(ctr, 0, sizeof(int), stream);   // graph-capture-safe
  srl_fused<<<dim3(NGRID), dim3(BLOCK), 0, stream>>>(
      hid, sids, amask, pids, a0ids, a1ids, out, ctr);
}

// Round 5
// 159.342 us; speedup vs baseline: 1.0836x; 1.0836x over previous
//
#include <hip/hip_runtime.h>

// SRL embeddings, fused single kernel — R7: byte-identical re-bench of the
// session champion (R2, 158.6us) as a noise-control experiment.
// Shapes fixed: B=16,S=16,L=128,D=768,A=8,T=5.
//
// R3-R6 post-mortem: four unrelated mechanisms (parallel Phase B, 8-wave
// blocks, two-kernel split, persistent work-stealing) each "cost" +8..14us.
// Four independent coincidences are less likely than session drift in the
// ~120us fixed harness-fill component (fills vary 58-61us across rounds;
// one fill dispatch even shows 58us at ~15KB traffic -> per-dispatch timing
// noise). This round discriminates: champion re-run.
//   ~159us  -> regressions were real; only traffic-reducing changes next.
//   ~166+   -> R3-R6 were within noise; re-anchor baseline accordingly.

namespace {
constexpr int Bc = 16, Sc = 16, Lc = 128, Dc = 768, Ac = 8, Tc = 5;
constexpr int NF4    = Dc / 4;          // 192 float4 per row
constexpr int CHUNK  = 32;              // float4 columns per block
constexpr int NCHUNK = NF4 / CHUNK;     // 6
constexpr int BLOCK  = 256;             // 4 waves
constexpr int RP     = BLOCK / CHUNK;   // 8 l-phases
constexpr int NSLOT  = 3 * Ac;          // 24 arg slots
constexpr int OUT1   = Bc * Sc * NF4;       // sentence output, float4 units
constexpr int OUTG   = Bc * Sc * Ac * NF4;  // per-arg-type output, float4 units
}

__global__ __launch_bounds__(BLOCK) void srl_fused(
    const float4* __restrict__ hid,
    const int*    __restrict__ sids,
    const int*    __restrict__ amask,
    const int*    __restrict__ pids,
    const int*    __restrict__ a0ids,
    const int*    __restrict__ a1ids,
    float4*       __restrict__ out)
{
  const int c   = blockIdx.x;           // column chunk 0..5
  const int bs  = blockIdx.y;           // (b,s) 0..255
  const int tid = threadIdx.x;
  const int q   = tid & (CHUNK - 1);    // float4 column within chunk
  const int r   = tid >> 5;             // l-phase 0..7

  __shared__ int    sid[Lc];
  __shared__ short  slist[NSLOT][Lc];
  __shared__ int    scnt[NSLOT];
  __shared__ float4 red[BLOCK];

  // Phase A: stage sentence ids; prefix length via __syncthreads_count.
  int mval = 0;
  if (tid < Lc) {
    sid[tid] = sids[bs * Lc + tid];
    mval     = amask[bs * Lc + tid];
  }
  const int len = __syncthreads_count(mval != 0);

  const float4* __restrict__ hrow = hid + (size_t)bs * Lc * NF4 + c * CHUNK;

  // Phase B (lanes 0..23 of wave 0, overlapped with pooling on other waves):
  // count matches for all 5 tokens in one sid scan, pick LAST valid t
  // (tok!=0 && cnt>0), build its match list.
  if (tid < NSLOT) {
    const int g = tid / Ac, a = tid % Ac;
    const int* ids = (g == 0 ? pids : (g == 1 ? a0ids : a1ids)) + (bs * Ac + a) * Tc;
    int tok[Tc], cnt[Tc];
#pragma unroll
    for (int t = 0; t < Tc; ++t) { tok[t] = ids[t]; cnt[t] = 0; }
    for (int l = 0; l < Lc; ++l) {
      const int v = sid[l];   // broadcast read
#pragma unroll
      for (int t = 0; t < Tc; ++t) cnt[t] += (v == tok[t]) ? 1 : 0;
    }
    int sel = 0, n = 0;
#pragma unroll
    for (int t = Tc - 1; t >= 0; --t) {
      if (n == 0 && tok[t] != 0 && cnt[t] > 0) { sel = tok[t]; n = cnt[t]; }
    }
    scnt[tid] = n;
    if (n > 0) {
      int k = 0;
      for (int l = 0; l < Lc; ++l)
        if (sid[l] == sel) slist[tid][k++] = (short)l;
    }
  }

  // Phase C: pooling partial sums over the valid prefix, l-split by r.
  float ax = 0.f, ay = 0.f, az = 0.f, aw = 0.f;
#pragma unroll 4
  for (int l = r; l < len; l += RP) {
    const float4 v = hrow[l * NF4 + q];
    ax += v.x; ay += v.y; az += v.z; aw += v.w;
  }
  red[tid] = make_float4(ax, ay, az, aw);
  __syncthreads();   // red ready; also publishes scnt/slist for Phase D

  // Phase C2: reduce the 8 l-phases, divide by len, write sentence embedding.
  if (tid < CHUNK) {
    float4 s = red[q];
#pragma unroll
    for (int p = 1; p < RP; ++p) {
      const float4 t = red[p * CHUNK + q];
      s.x += t.x; s.y += t.y; s.z += t.z; s.w += t.w;
    }
    const float inv = 1.0f / (float)(len > 0 ? len : 1);
    s.x *= inv; s.y *= inv; s.z *= inv; s.w *= inv;
    out[bs * NF4 + c * CHUNK + q] = s;
  }

  // Phase D: arg embeddings. 3 slots per l-phase; match rows hit L1/L2
  // (same columns streamed in Phase C).
  for (int j = r; j < NSLOT; j += RP) {
    const int n = scnt[j];
    float ox = 0.f, oy = 0.f, oz = 0.f, ow = 0.f;
    if (n > 0) {
      for (int i = 0; i < n; ++i) {
        const int l = (int)slist[j][i];   // broadcast read
        const float4 v = hrow[l * NF4 + q];
        ox += v.x; oy += v.y; oz += v.z; ow += v.w;
      }
      const float inv = 1.0f / (float)n;
      ox *= inv; oy *= inv; oz *= inv; ow *= inv;
    }
    const int g = j / Ac, a = j % Ac;
    out[OUT1 + g * OUTG + (bs * Ac + a) * NF4 + c * CHUNK + q] =
        make_float4(ox, oy, oz, ow);
  }
}

extern "C" void kernel_launch(void* const* d_in, const int* in_sizes, int n_in,
                              void* d_out, int out_size, void* d_ws, size_t ws_size,
                              hipStream_t stream) {
  const float4* hid   = (const float4*)d_in[0];
  const int*    sids  = (const int*)d_in[1];
  const int*    amask = (const int*)d_in[2];
  const int*    pids  = (const int*)d_in[3];
  const int*    a0ids = (const int*)d_in[4];
  const int*    a1ids = (const int*)d_in[5];
  float4*       out   = (float4*)d_out;

  srl_fused<<<dim3(NCHUNK, Bc * Sc), dim3(BLOCK), 0, stream>>>(
      hid, sids, amask, pids, a0ids, a1ids, out);
}